// Round 6
// baseline (129.010 us; speedup 1.0000x reference)
//
#include <hip/hip_runtime.h>
#include <stdint.h>

// Problem dims (fixed by reference setup_inputs)
#define NNODES 20000
#define NSRC   2048
#define DIN    128
#define KSPLIT 4
#define KPW    (NSRC / KSPLIT)   // 512 per wave

typedef short s16x8 __attribute__((ext_vector_type(8)));
typedef unsigned short u16x8 __attribute__((ext_vector_type(8)));
typedef float f32x4 __attribute__((ext_vector_type(4)));

// round-to-nearest-even f32 -> bf16 bits
static __device__ __forceinline__ unsigned short f2bf(float f) {
  union { float f; unsigned int u; } v; v.f = f;
  unsigned int r = v.u + 0x7FFFu + ((v.u >> 16) & 1u);
  return (unsigned short)(r >> 16);
}

static __device__ __forceinline__ s16x8 pack8(float4 a, float4 b) {
  s16x8 r;
  r[0] = (short)f2bf(a.x); r[1] = (short)f2bf(a.y);
  r[2] = (short)f2bf(a.z); r[3] = (short)f2bf(a.w);
  r[4] = (short)f2bf(b.x); r[5] = (short)f2bf(b.y);
  r[6] = (short)f2bf(b.z); r[7] = (short)f2bf(b.w);
  return r;
}

static __device__ __forceinline__ s16x8 load_cvt8(const float* __restrict__ p) {
  return pack8(*reinterpret_cast<const float4*>(p),
               *reinterpret_cast<const float4*>(p + 4));
}

// ---------------------------------------------------------------------------
// Kernel 1: supportT[j][s] = bf16( sum_k x[src_idx[s]][k] * W[k][j] )
// (unchanged — validated R2/R4)
// ---------------------------------------------------------------------------
__global__ __launch_bounds__(128) void support_kernel(
    const float* __restrict__ x, const float* __restrict__ W,
    const int* __restrict__ src_idx, unsigned short* __restrict__ supT) {
  __shared__ float xrows[8][DIN];
  const int j = threadIdx.x;
  const int s0 = blockIdx.x * 8;
#pragma unroll
  for (int i = 0; i < 8; ++i) {
    const int src = src_idx[s0 + i];
    xrows[i][j] = x[(size_t)src * DIN + j];
  }
  __syncthreads();
  float acc[8];
#pragma unroll
  for (int i = 0; i < 8; ++i) acc[i] = 0.f;
  for (int k = 0; k < DIN; ++k) {
    const float w = W[(size_t)k * DIN + j];
#pragma unroll
    for (int i = 0; i < 8; ++i) acc[i] += xrows[i][k] * w;
  }
  u16x8 o;
#pragma unroll
  for (int i = 0; i < 8; ++i) o[i] = f2bf(acc[i]);
  *reinterpret_cast<u16x8*>(&supT[(size_t)j * NSRC + s0]) = o;
}

// ---------------------------------------------------------------------------
// Kernel 2: out = LeakyReLU(A @ support) @ dense0_w^T
// R5: K-split 4-way. Block = 4 waves / 16 rows. Each wave: K=512 slice,
// independent (no barriers, no LDS in K-loop; plain register loads).
// Grid = 1250 blocks = 5000 waves (~19.5/CU — 8x R4's wave count).
// Epilogue: lane-wise partial reduce via LDS -> LeakyReLU -> act tile ->
// GEMM2 (2 n-tiles per wave).
// MFMA 16x16x32 bf16 layouts (validated R2/R4):
//   A-frag: lane l holds A[l&15][(l>>4)*8+e]; B-frag: B[(l>>4)*8+e][l&15]
//   C/D:    lane l holds C[(l>>4)*4+r][l&15]
// ---------------------------------------------------------------------------
__global__ __launch_bounds__(256) void fused_gcn_kernel(
    const float* __restrict__ A,             // [NNODES][NSRC] f32
    const unsigned short* __restrict__ supT, // [DIN][NSRC] bf16 bits
    const float* __restrict__ Wd,            // dense0_w [DIN][DIN] f32
    float* __restrict__ out) {               // [NNODES][DIN] f32
  const int tid = threadIdx.x;
  const int lane = tid & 63;
  const int wave = tid >> 6;                 // 0..3 -> K-slice
  const int r16 = lane & 15;
  const int g = lane >> 4;
  const int rowBase = blockIdx.x * 16;

  // red[w][n][lane][r]: partial C fragments of waves 1..3 (f32x4 per lane,
  // addr = lane*16B within each [64][4] slab -> linear, conflict-free b128).
  __shared__ float red[3][8 * 64 * 4];       // 24 KB
  __shared__ unsigned short act[16][136];    // 4.25 KB (row = 272B, 16B-align)

  f32x4 acc[8];
#pragma unroll
  for (int n = 0; n < 8; ++n) acc[n] = (f32x4){0.f, 0.f, 0.f, 0.f};

  const float* aRow = A + (size_t)(rowBase + r16) * NSRC + wave * KPW;
  const unsigned short* bBase =
      supT + (size_t)r16 * NSRC + wave * KPW + g * 8;

  // K-loop: 16 chunks of 32. 1 A-frag load (f32->bf16 cvt) + 8 B-frag loads
  // + 8 MFMA per chunk. No barriers; compiler schedules vmcnt.
#pragma unroll 2
  for (int kk = 0; kk < KPW / 32; ++kk) {
    const s16x8 a = load_cvt8(aRow + kk * 32 + g * 8);
#pragma unroll
    for (int n = 0; n < 8; ++n) {
      const s16x8 b = *reinterpret_cast<const s16x8*>(
          bBase + (size_t)n * 16 * NSRC + kk * 32);
      acc[n] = __builtin_amdgcn_mfma_f32_16x16x32_bf16(a, b, acc[n], 0, 0, 0);
    }
  }

  // ---- cross-wave reduction (lane-wise: same lane = same (row,col)) -------
  if (wave != 0) {
#pragma unroll
    for (int n = 0; n < 8; ++n)
      *reinterpret_cast<f32x4*>(&red[wave - 1][(n * 64 + lane) * 4]) = acc[n];
  }
  __syncthreads();
  if (wave == 0) {
#pragma unroll
    for (int w = 0; w < 3; ++w)
#pragma unroll
      for (int n = 0; n < 8; ++n) {
        const f32x4 p =
            *reinterpret_cast<const f32x4*>(&red[w][(n * 64 + lane) * 4]);
        acc[n] += p;
      }
    // LeakyReLU + act tile (bf16) for GEMM2
#pragma unroll
    for (int n = 0; n < 8; ++n)
#pragma unroll
      for (int r = 0; r < 4; ++r) {
        float v = acc[n][r];
        v = (v >= 0.f) ? v : 0.01f * v;
        act[g * 4 + r][n * 16 + r16] = f2bf(v);
      }
  }
  __syncthreads();

  // ---- GEMM2: out[i][j] = sum_k act[i][k] * Wd[j][k]; 2 n-tiles per wave --
  f32x4 acc2[2];
  acc2[0] = (f32x4){0.f, 0.f, 0.f, 0.f};
  acc2[1] = (f32x4){0.f, 0.f, 0.f, 0.f};
#pragma unroll
  for (int k2 = 0; k2 < 4; ++k2) {
    const int k = k2 * 32 + g * 8;
    const s16x8 a2 = *reinterpret_cast<const s16x8*>(&act[r16][k]);
#pragma unroll
    for (int t = 0; t < 2; ++t) {
      const int n2 = wave * 2 + t;
      const s16x8 b2 = load_cvt8(Wd + (size_t)(n2 * 16 + r16) * DIN + k);
      acc2[t] =
          __builtin_amdgcn_mfma_f32_16x16x32_bf16(a2, b2, acc2[t], 0, 0, 0);
    }
  }
#pragma unroll
  for (int t = 0; t < 2; ++t)
#pragma unroll
    for (int r = 0; r < 4; ++r)
      out[(size_t)(rowBase + g * 4 + r) * DIN + (wave * 2 + t) * 16 + r16] =
          acc2[t][r];
}

// ---------------------------------------------------------------------------
extern "C" void kernel_launch(void* const* d_in, const int* in_sizes, int n_in,
                              void* d_out, int out_size, void* d_ws, size_t ws_size,
                              hipStream_t stream) {
  const float* x   = (const float*)d_in[0];   // [20000][128]
  const float* A   = (const float*)d_in[1];   // [20000][2048]
  const float* W   = (const float*)d_in[2];   // [128][128]
  const float* Wd  = (const float*)d_in[3];   // [128][128]
  const int*   src = (const int*)d_in[4];     // [2048]
  float* out = (float*)d_out;

  unsigned short* supT = (unsigned short*)d_ws;  // 128*2048*2 = 512 KB

  support_kernel<<<NSRC / 8, 128, 0, stream>>>(x, W, src, supT);
  fused_gcn_kernel<<<NNODES / 16, 256, 0, stream>>>(A, supT, Wd, out);
}

// Round 7
// 65.308 us; speedup vs baseline: 1.9754x; 1.9754x over previous
//
#include <hip/hip_runtime.h>
#include <stdint.h>

// Problem dims (fixed by reference setup_inputs)
#define NNODES 20000
#define NSRC   2048
#define DIN    128

typedef short s16x8 __attribute__((ext_vector_type(8)));
typedef unsigned short u16x8 __attribute__((ext_vector_type(8)));
typedef float f32x4 __attribute__((ext_vector_type(4)));

// round-to-nearest-even f32 -> bf16 bits
static __device__ __forceinline__ unsigned short f2bf(float f) {
  union { float f; unsigned int u; } v; v.f = f;
  unsigned int r = v.u + 0x7FFFu + ((v.u >> 16) & 1u);
  return (unsigned short)(r >> 16);
}

static __device__ __forceinline__ s16x8 pack8(float4 a, float4 b) {
  s16x8 r;
  r[0] = (short)f2bf(a.x); r[1] = (short)f2bf(a.y);
  r[2] = (short)f2bf(a.z); r[3] = (short)f2bf(a.w);
  r[4] = (short)f2bf(b.x); r[5] = (short)f2bf(b.y);
  r[6] = (short)f2bf(b.z); r[7] = (short)f2bf(b.w);
  return r;
}

static __device__ __forceinline__ s16x8 load_cvt8(const float* __restrict__ p) {
  return pack8(*reinterpret_cast<const float4*>(p),
               *reinterpret_cast<const float4*>(p + 4));
}

#define GLL16(g, l)                                                          \
  __builtin_amdgcn_global_load_lds(                                          \
      (const __attribute__((address_space(1))) void*)(g),                    \
      (__attribute__((address_space(3))) void*)(l), 16, 0, 0)

// ---------------------------------------------------------------------------
// Kernel 1: support = x[src_idx] @ W, written DIRECTLY in MFMA-fragment-linear
// order: supTp[((kk*8 + n)*64 + lane)*8 + e] = bf16(support[kk*32 + (lane>>4)*8
// + e][n*16 + (lane&15)]). Thread j's 8 sources (s0..s0+7) are one e-run ->
// one contiguous u16x8 store; adjacent j -> adjacent 16B chunks (coalesced).
// ---------------------------------------------------------------------------
__global__ __launch_bounds__(128) void support_kernel(
    const float* __restrict__ x, const float* __restrict__ W,
    const int* __restrict__ src_idx, unsigned short* __restrict__ supTp) {
  __shared__ float xrows[8][DIN];
  const int j = threadIdx.x;           // output feature 0..127
  const int s0 = blockIdx.x * 8;       // first source (k-index) of this block
#pragma unroll
  for (int i = 0; i < 8; ++i) {
    const int src = src_idx[s0 + i];
    xrows[i][j] = x[(size_t)src * DIN + j];
  }
  __syncthreads();
  float acc[8];
#pragma unroll
  for (int i = 0; i < 8; ++i) acc[i] = 0.f;
  for (int k = 0; k < DIN; ++k) {
    const float w = W[(size_t)k * DIN + j];   // coalesced across threads
#pragma unroll
    for (int i = 0; i < 8; ++i) acc[i] += xrows[i][k] * w;  // LDS broadcast
  }
  u16x8 o;
#pragma unroll
  for (int i = 0; i < 8; ++i) o[i] = f2bf(acc[i]);
  const int kk = s0 >> 5;              // 32-wide k-chunk
  const int g2 = (s0 >> 3) & 3;        // k-slot group within chunk
  const int n = j >> 4;                // n-tile
  const int lane = (j & 15) + g2 * 16; // MFMA lane holding these 8 elements
  *reinterpret_cast<u16x8*>(&supTp[(size_t)((kk * 8 + n) * 64 + lane) * 8]) = o;
}

// ---------------------------------------------------------------------------
// Kernel 2: out = LeakyReLU(A @ support) @ dense0_w^T
// Block = 128 thr / 2 waves; wave w owns rows rowBase + w*16..+15. Grid 625.
// K-loop: 32 chunks of BK=64, double-buffered LDS, all staging via
// global_load_lds with CONTIGUOUS per-instruction sources:
//   A: 8 instrs/chunk (4 rows x 256B segments), XOR-slot-swizzled source so
//      linear LDS + swizzled read = conflict-free (2-way) fragment ds_reads.
//   B: 16 instrs/chunk, 1KB fully contiguous each (supTp is fragment-linear).
// Sync: raw s_barrier + counted vmcnt(12) (12 gll/wave/chunk); never 0 in loop.
// MFMA 16x16x32 bf16 layouts (validated R2/R4/R6):
//   A-frag: lane l holds A[l&15][(l>>4)*8+e]; B-frag: B[(l>>4)*8+e][l&15]
//   C/D:    lane l holds C[(l>>4)*4+r][l&15]
// ---------------------------------------------------------------------------
__global__ __launch_bounds__(128) void fused_gcn_kernel(
    const float* __restrict__ A,             // [NNODES][NSRC] f32
    const unsigned short* __restrict__ supTp,// fragment-packed, 512 KB
    const float* __restrict__ Wd,            // dense0_w [DIN][DIN] f32
    float* __restrict__ out) {               // [NNODES][DIN] f32
  const int tid = threadIdx.x;
  const int lane = tid & 63;
  const int w = tid >> 6;                    // wave 0..1
  const int r16 = lane & 15;
  const int g = lane >> 4;
  const int rowBase = blockIdx.x * 32;

  // pool: Ap [2][32 rows][64 f32] = 16 KB | Bp [2][2 kk][8 n][64 lane][8 e]
  // = 32 KB. After the K-loop (post-barrier) the first 8.7 KB are reused as
  // the per-wave act tiles.
  __shared__ __attribute__((aligned(16))) unsigned char pool[49152];
  float* Ap = (float*)pool;
  unsigned short* Bp = (unsigned short*)(pool + 16384);

  f32x4 acc[8];
#pragma unroll
  for (int n = 0; n < 8; ++n) acc[n] = (f32x4){0.f, 0.f, 0.f, 0.f};

  // ---- STAGE chunk c (cols c*64..+63) into buffer `buf` -------------------
  // A: instr i = w*4+i2 covers rows 4i..4i+3 (4 x 256B segments). Source col
  //    slot pre-swizzled: slot_src = (lane&15) ^ (row&7)  (involution).
  // B: instr iB = w*8+i2 -> (kk2=iB>>3, n=iB&7): 64 lanes x 16B contiguous.
#define STAGE(buf, c)                                                         \
  {                                                                           \
    _Pragma("unroll") for (int i2 = 0; i2 < 4; ++i2) {                        \
      const int i = w * 4 + i2;                                               \
      const int row = 4 * i + (lane >> 4);                                    \
      GLL16(A + (size_t)(rowBase + row) * NSRC + (c) * 64 +                   \
                (((lane & 15) ^ (row & 7)) << 2),                             \
            Ap + (buf) * 2048 + i * 256);                                     \
    }                                                                         \
    _Pragma("unroll") for (int i2 = 0; i2 < 8; ++i2) {                        \
      const int iB = w * 8 + i2;                                              \
      GLL16(supTp +                                                           \
                ((size_t)(((c) * 2 + (iB >> 3)) * 8 + (iB & 7)) * 64 + lane)  \
                    * 8,                                                      \
            Bp + (buf) * 8192 + iB * 512);                                    \
    }                                                                         \
  }

  // ---- COMPUTE chunk in buffer `buf` (per wave: rows w*16..+15) -----------
#define COMPUTE(buf)                                                          \
  {                                                                           \
    _Pragma("unroll") for (int kk2 = 0; kk2 < 2; ++kk2) {                     \
      const float* rb = Ap + (buf) * 2048 + (w * 16 + r16) * 64;              \
      const float4 lo = *reinterpret_cast<const float4*>(                     \
          &rb[((kk2 * 8 + g * 2) ^ (r16 & 7)) << 2]);                         \
      const float4 hi = *reinterpret_cast<const float4*>(                     \
          &rb[((kk2 * 8 + g * 2 + 1) ^ (r16 & 7)) << 2]);                     \
      const s16x8 a = pack8(lo, hi);                                          \
      _Pragma("unroll") for (int n = 0; n < 8; ++n) {                         \
        const s16x8 b = *reinterpret_cast<const s16x8*>(                      \
            &Bp[(buf) * 8192 + ((kk2 * 8 + n) * 64 + lane) * 8]);             \
        acc[n] =                                                              \
            __builtin_amdgcn_mfma_f32_16x16x32_bf16(a, b, acc[n], 0, 0, 0);   \
      }                                                                       \
    }                                                                         \
  }

  STAGE(0, 0);
  for (int c = 0; c < 31; ++c) {
    STAGE((c & 1) ^ 1, c + 1);
    asm volatile("s_waitcnt vmcnt(12)" ::: "memory");  // chunk c arrived
    __builtin_amdgcn_s_barrier();                      // all waves' staging in
    COMPUTE(c & 1);
    __builtin_amdgcn_s_barrier();                      // all reads done
  }
  asm volatile("s_waitcnt vmcnt(0)" ::: "memory");
  __builtin_amdgcn_s_barrier();
  COMPUTE(1);  // chunk 31 -> buffer 1

  // ---- epilogue: LeakyReLU -> act (reuse pool) -> GEMM2 -> store ----------
  __builtin_amdgcn_s_barrier();  // everyone's MFMA reads retired; pool free
  unsigned short* actw = (unsigned short*)pool + w * 2176;  // [16][136]
#pragma unroll
  for (int n = 0; n < 8; ++n)
#pragma unroll
    for (int r = 0; r < 4; ++r) {
      float v = acc[n][r];
      v = (v >= 0.f) ? v : 0.01f * v;
      actw[(g * 4 + r) * 136 + n * 16 + r16] = f2bf(v);
    }
  // own-wave write->read; compiler orders via lgkmcnt

  f32x4 acc2[8];
#pragma unroll
  for (int n = 0; n < 8; ++n) acc2[n] = (f32x4){0.f, 0.f, 0.f, 0.f};
#pragma unroll
  for (int k2 = 0; k2 < 4; ++k2) {
    const int k = k2 * 32 + g * 8;
    const s16x8 a2 = *reinterpret_cast<const s16x8*>(&actw[r16 * 136 + k]);
#pragma unroll
    for (int n = 0; n < 8; ++n) {
      const s16x8 b2 = load_cvt8(Wd + (size_t)(n * 16 + r16) * DIN + k);
      acc2[n] =
          __builtin_amdgcn_mfma_f32_16x16x32_bf16(a2, b2, acc2[n], 0, 0, 0);
    }
  }
#pragma unroll
  for (int n = 0; n < 8; ++n)
#pragma unroll
    for (int r = 0; r < 4; ++r)
      out[(size_t)(rowBase + w * 16 + g * 4 + r) * DIN + n * 16 + r16] =
          acc2[n][r];
}

// ---------------------------------------------------------------------------
extern "C" void kernel_launch(void* const* d_in, const int* in_sizes, int n_in,
                              void* d_out, int out_size, void* d_ws, size_t ws_size,
                              hipStream_t stream) {
  const float* x   = (const float*)d_in[0];   // [20000][128]
  const float* A   = (const float*)d_in[1];   // [20000][2048]
  const float* W   = (const float*)d_in[2];   // [128][128]
  const float* Wd  = (const float*)d_in[3];   // [128][128]
  const int*   src = (const int*)d_in[4];     // [2048]
  float* out = (float*)d_out;

  unsigned short* supTp = (unsigned short*)d_ws;  // 512 KB, fragment-packed

  support_kernel<<<NSRC / 8, 128, 0, stream>>>(x, W, src, supTp);
  fused_gcn_kernel<<<NNODES / 32, 128, 0, stream>>>(A, supTp, Wd, out);
}